// Round 2
// 2482.174 us; speedup vs baseline: 1.2749x; 1.2749x over previous
//
#include <hip/hip_runtime.h>
#include <math.h>
#include <stdint.h>

// Problem constants
static constexpr int B_ = 128;
static constexpr int T_ = 64;
static constexpr int E_ = 2048;
static constexpr int H_ = 1024;
static constexpr int R_ = 8;
static constexpr int H3_ = 3 * H_;  // 3072

typedef unsigned short u16;
typedef __attribute__((ext_vector_type(8))) __bf16 bf16x8;
typedef __attribute__((ext_vector_type(4))) float f32x4;

__device__ __forceinline__ u16 f2bf(float f) {
    uint32_t x = __float_as_uint(f);
    x += 0x7fffu + ((x >> 16) & 1u);      // round-to-nearest-even
    return (u16)(x >> 16);
}
__device__ __forceinline__ float bf2f(u16 u) {
    return __uint_as_float(((uint32_t)u) << 16);
}

// async global->LDS, 16B per lane; LDS dest = wave-uniform base + lane*16
__device__ __forceinline__ void async_cp16(const u16* g, u16* l) {
    auto* g1 = (const __attribute__((address_space(1))) u16*)g;
    auto* l3 = (__attribute__((address_space(3))) u16*)(uintptr_t)l;
    __builtin_amdgcn_global_load_lds((const __attribute__((address_space(1))) void*)g1,
                                     (__attribute__((address_space(3))) void*)l3,
                                     16, 0, 0);
}

// ---------------------------------------------------------------------------
__global__ __launch_bounds__(256) void zero_kernel(float* __restrict__ p, int n) {
    int i = blockIdx.x * 256 + threadIdx.x;
    if (i < n) p[i] = 0.0f;
}

// fp32 -> bf16 pack: dst[r*cols+c] = bf16(src[r*src_ld + col0 + c])
__global__ __launch_bounds__(256) void conv_bf(
    const float* __restrict__ src, int src_ld, int col0, int cols,
    u16* __restrict__ dst, int total4)
{
    int i4 = blockIdx.x * 256 + threadIdx.x;
    if (i4 >= total4) return;
    int i = i4 * 4;
    int r = i / cols, c = i - r * cols;
    const float4 v = *(const float4*)(src + (size_t)r * src_ld + col0 + c);
    ushort4 o;
    o.x = f2bf(v.x); o.y = f2bf(v.y); o.z = f2bf(v.z); o.w = f2bf(v.w);
    *(ushort4*)(dst + i) = o;
}

// ---------------------------------------------------------------------------
// Fused Phase 1 MFMA GEMM over all three weight sets.
//   C[m, which, n] = bf16( sum_k X[row(m),k]*W1[which*3072+n, k] + bias_which[n] )
// X = enc_bf (ld E_), W1 packed bf16 [3*3072 x 2048] (s|a|o),
// GI = packed output, 3 consecutive [B*Tc x 3072] bf16 buffers.
// 128x128 tile, BK=32, double-buffered 2-phase loop, 256 thr (4 waves 2x2).
// grid (72, B*Tc/128): blockIdx.x -> which = bx/24, n0 = (bx%24)*128.
// ---------------------------------------------------------------------------
__global__ __launch_bounds__(256) void mfma_p1f(
    const u16* __restrict__ X, int t0, int tcshift,
    const u16* __restrict__ W1,
    const float* __restrict__ bs, const float* __restrict__ ba,
    const float* __restrict__ bo,
    u16* __restrict__ GI, size_t GI_elems)
{
    __shared__ u16 As[2][128 * 32];
    __shared__ u16 Bs[2][128 * 32];
    __shared__ int rowoff[128];
    const int tid = threadIdx.x;
    const int which = blockIdx.x / 24;
    const int n0 = (blockIdx.x % 24) * 128;
    const int m0 = blockIdx.y * 128;
    const int tcmask = (1 << tcshift) - 1;

    const u16* W = W1 + (size_t)which * H3_ * E_;
    const float* bias = (which == 0) ? bs : (which == 1) ? ba : bo;
    u16* C = GI + (size_t)which * GI_elems;

    if (tid < 128) {
        int m = m0 + tid;
        rowoff[tid] = ((m >> tcshift) * T_ + t0 + (m & tcmask)) * E_;
    }
    __syncthreads();

    const int lane = tid & 63;
    const int wm = ((tid >> 6) & 1) * 64;
    const int wn = (tid >> 7) * 64;
    const int fr = lane & 15;            // fragment row (m for A, n for B)
    const int kq = (lane >> 4) * 8;      // k-quad offset
    const int wbase = (tid & 192) * 8;   // wave-uniform LDS chunk base (elems)

    f32x4 acc[4][4] = {};

    auto stage = [&](int buf, int k0) {
#pragma unroll
        for (int p = 0; p < 2; ++p) {
            int c = p * 256 + tid;
            int row = c >> 2, kc = (c & 3) * 8;
            async_cp16(X + rowoff[row] + k0 + kc, &As[buf][p * 2048 + wbase]);
            async_cp16(W + (size_t)(n0 + row) * E_ + k0 + kc, &Bs[buf][p * 2048 + wbase]);
        }
    };
    auto compute = [&](int buf) {
        bf16x8 a[4], b[4];
#pragma unroll
        for (int i = 0; i < 4; ++i) {
            a[i] = *(const bf16x8*)&As[buf][(wm + i * 16 + fr) * 32 + kq];
            b[i] = *(const bf16x8*)&Bs[buf][(wn + i * 16 + fr) * 32 + kq];
        }
#pragma unroll
        for (int mt = 0; mt < 4; ++mt)
#pragma unroll
            for (int nt = 0; nt < 4; ++nt)
                acc[mt][nt] = __builtin_amdgcn_mfma_f32_16x16x32_bf16(
                    a[mt], b[nt], acc[mt][nt], 0, 0, 0);
    };

    stage(0, 0);
    __syncthreads();                 // drains vmcnt: buf0 ready
    int cur = 0;
    for (int k0 = 32; k0 < E_; k0 += 32) {
        stage(cur ^ 1, k0);          // issue next-tile loads (overlap w/ compute)
        compute(cur);
        __syncthreads();             // drains vmcnt+lgkm: next buf ready, cur free
        cur ^= 1;
    }
    compute(cur);

#pragma unroll
    for (int mt = 0; mt < 4; ++mt)
#pragma unroll
        for (int nt = 0; nt < 4; ++nt) {
            int n = n0 + wn + nt * 16 + fr;
            float bv = bias[n];
#pragma unroll
            for (int i = 0; i < 4; ++i) {
                int m = m0 + wm + mt * 16 + (lane >> 4) * 4 + i;
                C[(size_t)m * H3_ + n] = f2bf(acc[mt][nt][i] + bv);
            }
        }
}

// ---------------------------------------------------------------------------
// Per-step MFMA GEMM over gathered state rows. 64x128 tile, grid (24, 20).
// Global output row mo = blockIdx.y*64 + local m, G layout [1280 x 3072]:
//   [0,128)    giS = A[b,adr] @ Whsi^T
//   [128,256)  ghS = A[b,spk] @ Whs^T
//   [256,384)  giA = A[b,spk] @ Whai^T
//   [384,512)  ghA = A[b,adr] @ Wha^T
//   [512,1280) ghO = A[b,oth_j] @ Who^T
// K = H_ = 1024, BK=32, double-buffered 2-phase loop, 4 waves (2m x 2n).
// ---------------------------------------------------------------------------
__global__ __launch_bounds__(256) void mfma_step(
    const u16* __restrict__ Abf, const int* __restrict__ dig, int t,
    const u16* __restrict__ Whsi, const u16* __restrict__ Whs,
    const u16* __restrict__ Whai, const u16* __restrict__ Wha,
    const u16* __restrict__ Who, float* __restrict__ G)
{
    __shared__ u16 As[2][64 * 32];
    __shared__ u16 Bs[2][128 * 32];
    __shared__ int rowoff[64];
    const int tid = threadIdx.x;
    const int n0 = blockIdx.x * 128;
    const int row0 = blockIdx.y * 64;

    const u16* W;
    if      (row0 < 128) W = Whsi;
    else if (row0 < 256) W = Whs;
    else if (row0 < 384) W = Whai;
    else if (row0 < 512) W = Wha;
    else                 W = Who;

    if (tid < 64) {
        int mo = row0 + tid;
        int b, role;
        if (mo < 512) {
            b = mo & 127;
            int kind = mo >> 7;
            int spk = dig[(b * T_ + t) * 2 + 0];
            int adr = dig[(b * T_ + t) * 2 + 1];
            role = (kind == 0 || kind == 3) ? adr : spk;
        } else {
            int o = mo - 512;
            b = o / 6;
            int j = o - b * 6;
            int spk = dig[(b * T_ + t) * 2 + 0];
            int adr = dig[(b * T_ + t) * 2 + 1];
            int cnt = 0; role = 0;
            for (int r = 0; r < R_; ++r) {
                if (r != spk && r != adr) {
                    if (cnt == j) { role = r; break; }
                    ++cnt;
                }
            }
        }
        rowoff[tid] = (b * R_ + role) * H_;
    }
    __syncthreads();

    const int lane = tid & 63;
    const int wid = tid >> 6;
    const int wm = (wid & 1) * 32;
    const int wn = (wid >> 1) * 64;
    const int fr = lane & 15;
    const int kq = (lane >> 4) * 8;
    const int wbase = (tid & 192) * 8;

    f32x4 acc[2][4] = {};

    auto stage = [&](int buf, int k0) {
        {   // A: 64 rows x 32 cols = 2048 elems, one 256-thread round
            int row = tid >> 2, kc = (tid & 3) * 8;
            async_cp16(Abf + rowoff[row] + k0 + kc, &As[buf][wbase]);
        }
#pragma unroll
        for (int p = 0; p < 2; ++p) {  // B: 128 rows x 32 cols
            int c = p * 256 + tid;
            int row = c >> 2, kc = (c & 3) * 8;
            async_cp16(W + (size_t)(n0 + row) * H_ + k0 + kc, &Bs[buf][p * 2048 + wbase]);
        }
    };
    auto compute = [&](int buf) {
        bf16x8 a[2], b[4];
#pragma unroll
        for (int i = 0; i < 2; ++i)
            a[i] = *(const bf16x8*)&As[buf][(wm + i * 16 + fr) * 32 + kq];
#pragma unroll
        for (int j = 0; j < 4; ++j)
            b[j] = *(const bf16x8*)&Bs[buf][(wn + j * 16 + fr) * 32 + kq];
#pragma unroll
        for (int mt = 0; mt < 2; ++mt)
#pragma unroll
            for (int nt = 0; nt < 4; ++nt)
                acc[mt][nt] = __builtin_amdgcn_mfma_f32_16x16x32_bf16(
                    a[mt], b[nt], acc[mt][nt], 0, 0, 0);
    };

    stage(0, 0);
    __syncthreads();
    int cur = 0;
    for (int k0 = 32; k0 < H_; k0 += 32) {
        stage(cur ^ 1, k0);
        compute(cur);
        __syncthreads();
        cur ^= 1;
    }
    compute(cur);

#pragma unroll
    for (int mt = 0; mt < 2; ++mt)
#pragma unroll
        for (int nt = 0; nt < 4; ++nt) {
            int n = n0 + wn + nt * 16 + fr;
#pragma unroll
            for (int i = 0; i < 4; ++i) {
                int mo = row0 + wm + mt * 16 + (lane >> 4) * 4 + i;
                G[(size_t)mo * H3_ + n] = acc[mt][nt][i];
            }
        }
}

// ---------------------------------------------------------------------------
// Gate kernel. Block per (b, r). Writes fp32 state (Anew) + bf16 copy (Abf).
// ---------------------------------------------------------------------------
__global__ __launch_bounds__(256) void gate_kernel(
    const float* __restrict__ Aold, float* __restrict__ Anew,
    u16* __restrict__ Abf,
    const int* __restrict__ dig, int t, int tloc, int Tc,
    const u16* __restrict__ GIX, const u16* __restrict__ GIA,
    const u16* __restrict__ GIO, const float* __restrict__ G,
    const float* __restrict__ ws_bhh, const float* __restrict__ wa_bhh,
    const float* __restrict__ wo_bhh)
{
    const int blk = blockIdx.x;       // b*R + r
    const int b = blk >> 3, r = blk & 7;
    const int spk = dig[(b * T_ + t) * 2 + 0];
    const int adr = dig[(b * T_ + t) * 2 + 1];
    const size_t gi_row = (size_t)(b * Tc + tloc) * H3_;

    const u16* gi_pre;
    const float* gi_add;   // may be null (others)
    const float* gh;
    const float* bhh;
    if (r == spk) {
        gi_pre = GIX + gi_row;
        gi_add = G + (size_t)b * H3_;
        gh     = G + (size_t)(128 + b) * H3_;
        bhh    = ws_bhh;
    } else if (r == adr) {
        gi_pre = GIA + gi_row;
        gi_add = G + (size_t)(256 + b) * H3_;
        gh     = G + (size_t)(384 + b) * H3_;
        bhh    = wa_bhh;
    } else {
        int oidx = r - (spk < r ? 1 : 0) - (adr < r ? 1 : 0);
        gi_pre = GIO + gi_row;
        gi_add = nullptr;
        gh     = G + (size_t)(512 + b * 6 + oidx) * H3_;
        bhh    = wo_bhh;
    }

    const size_t hoff = (size_t)(b * R_ + r) * H_;
    for (int i = threadIdx.x; i < H_; i += 256) {
        float gir = bf2f(gi_pre[i]);
        float giz = bf2f(gi_pre[H_ + i]);
        float gin = bf2f(gi_pre[2 * H_ + i]);
        if (gi_add) {
            gir += gi_add[i];
            giz += gi_add[H_ + i];
            gin += gi_add[2 * H_ + i];
        }
        float ghr = gh[i]          + bhh[i];
        float ghz = gh[H_ + i]     + bhh[H_ + i];
        float ghn = gh[2 * H_ + i] + bhh[2 * H_ + i];

        float rg = 1.0f / (1.0f + __expf(-(gir + ghr)));
        float zg = 1.0f / (1.0f + __expf(-(giz + ghz)));
        float ng = tanhf(gin + rg * ghn);
        float h  = Aold[hoff + i];
        float o  = (1.0f - zg) * ng + zg * h;
        Anew[hoff + i] = o;
        Abf[hoff + i]  = f2bf(o);
    }
}

// ---------------------------------------------------------------------------
extern "C" void kernel_launch(void* const* d_in, const int* in_sizes, int n_in,
                              void* d_out, int out_size, void* d_ws, size_t ws_size,
                              hipStream_t stream) {
    const float* enc    = (const float*)d_in[0];
    const int*   dig    = (const int*)d_in[1];
    const float* ws_ih  = (const float*)d_in[2];
    const float* ws_hh  = (const float*)d_in[3];
    const float* ws_bih = (const float*)d_in[4];
    const float* ws_bhh = (const float*)d_in[5];
    const float* wa_ih  = (const float*)d_in[6];
    const float* wa_hh  = (const float*)d_in[7];
    const float* wa_bih = (const float*)d_in[8];
    const float* wa_bhh = (const float*)d_in[9];
    const float* wo_ih  = (const float*)d_in[10];
    const float* wo_hh  = (const float*)d_in[11];
    const float* wo_bih = (const float*)d_in[12];
    const float* wo_bhh = (const float*)d_in[13];

    float* A0 = (float*)d_out;                    // (B, R, H) final output

    // ---- workspace layout (bytes) ----
    char* p = (char*)d_ws;
    auto take = [&](size_t bytes) { char* q = p; p += (bytes + 255) & ~(size_t)255; return q; };
    u16*   enc_bf = (u16*)  take((size_t)B_ * T_ * E_ * 2);          // 33.6 MB
    u16*   W1     = (u16*)  take((size_t)3 * H3_ * E_ * 2);          // 37.7 MB packed s|a|o
    u16*   W1s    = W1;
    u16*   W1a    = W1 + (size_t)H3_ * E_;
    u16*   W1o    = W1a + (size_t)H3_ * E_;
    u16*   Whsi   = (u16*)  take((size_t)H3_ * H_ * 2);              // 6.3 MB
    u16*   Whai   = (u16*)  take((size_t)H3_ * H_ * 2);
    u16*   Whs    = (u16*)  take((size_t)H3_ * H_ * 2);
    u16*   Wha    = (u16*)  take((size_t)H3_ * H_ * 2);
    u16*   Who    = (u16*)  take((size_t)H3_ * H_ * 2);
    u16*   Abf    = (u16*)  take((size_t)B_ * R_ * H_ * 2);          // 2 MB
    float* A1     = (float*)take((size_t)B_ * R_ * H_ * 4);          // 4 MB
    float* G      = (float*)take((size_t)1280 * H3_ * 4);            // 15.7 MB
    size_t fixed = (size_t)(p - (char*)d_ws);

    // chunk size: largest power-of-two Tc <= 64 fitting GI (3 sets, bf16)
    const size_t per_t = (size_t)3 * B_ * H3_ * 2;                   // 2.36 MB/step
    int Tc = 64;
    while (Tc > 1 && fixed + per_t * (size_t)Tc > ws_size) Tc >>= 1;
    int tcshift = 0;
    while ((1 << tcshift) < Tc) ++tcshift;
    const size_t GI_elems = (size_t)B_ * Tc * H3_;
    u16* GI  = (u16*)take(3 * GI_elems * 2);                         // packed X|A|O
    u16* GIX = GI;
    u16* GIA = GI + GI_elems;
    u16* GIO = GIA + GI_elems;

    dim3 blk(256);
    const size_t A_sz = (size_t)B_ * R_ * H_;

    // zero fp32 state (d_out) and bf16 state copy
    zero_kernel<<<dim3((int)((A_sz + 255) / 256)), blk, 0, stream>>>(A0, (int)A_sz);
    zero_kernel<<<dim3((int)((A_sz / 2 + 255) / 256)), blk, 0, stream>>>((float*)Abf, (int)(A_sz / 2));

    // ---- one-time bf16 conversions ----
    {
        int t4;
        t4 = B_ * T_ * E_ / 4;
        conv_bf<<<dim3((t4 + 255) / 256), blk, 0, stream>>>(enc, E_, 0, E_, enc_bf, t4);
        t4 = H3_ * E_ / 4;
        conv_bf<<<dim3((t4 + 255) / 256), blk, 0, stream>>>(ws_ih, E_ + H_, 0, E_, W1s, t4);
        conv_bf<<<dim3((t4 + 255) / 256), blk, 0, stream>>>(wa_ih, E_ + H_, 0, E_, W1a, t4);
        conv_bf<<<dim3((t4 + 255) / 256), blk, 0, stream>>>(wo_ih, E_, 0, E_, W1o, t4);
        t4 = H3_ * H_ / 4;
        conv_bf<<<dim3((t4 + 255) / 256), blk, 0, stream>>>(ws_ih, E_ + H_, E_, H_, Whsi, t4);
        conv_bf<<<dim3((t4 + 255) / 256), blk, 0, stream>>>(wa_ih, E_ + H_, E_, H_, Whai, t4);
        conv_bf<<<dim3((t4 + 255) / 256), blk, 0, stream>>>(ws_hh, H_, 0, H_, Whs, t4);
        conv_bf<<<dim3((t4 + 255) / 256), blk, 0, stream>>>(wa_hh, H_, 0, H_, Wha, t4);
        conv_bf<<<dim3((t4 + 255) / 256), blk, 0, stream>>>(wo_hh, H_, 0, H_, Who, t4);
    }

    float* Aold = A0;
    float* Anew = A1;
    for (int t0 = 0; t0 < T_; t0 += Tc) {
        // Phase 1 (chunk): all three input-side GEMMs fused in one dispatch.
        dim3 g1(72, (B_ * Tc) / 128);
        mfma_p1f<<<g1, blk, 0, stream>>>(enc_bf, t0, tcshift, W1,
                                         ws_bih, wa_bih, wo_bih, GI, GI_elems);

        // Phase 2: sequential recurrence within the chunk.
        for (int t = t0; t < t0 + Tc; ++t) {
            mfma_step<<<dim3(24, 20), blk, 0, stream>>>(
                Abf, dig, t, Whsi, Whs, Whai, Wha, Who, G);
            gate_kernel<<<dim3(B_ * R_), blk, 0, stream>>>(
                Aold, Anew, Abf, dig, t, t - t0, Tc, GIX, GIA, GIO, G,
                ws_bhh, wa_bhh, wo_bhh);
            float* tmp = Aold; Aold = Anew; Anew = tmp;
        }
    }
    // T_ = 64 total steps (even): final state lands in A0 == d_out.
}

// Round 3
// 2167.818 us; speedup vs baseline: 1.4597x; 1.1450x over previous
//
#include <hip/hip_runtime.h>
#include <math.h>
#include <stdint.h>

// Problem constants
static constexpr int B_ = 128;
static constexpr int T_ = 64;
static constexpr int E_ = 2048;
static constexpr int H_ = 1024;
static constexpr int R_ = 8;
static constexpr int H3_ = 3 * H_;  // 3072

typedef unsigned short u16;
typedef __attribute__((ext_vector_type(8))) __bf16 bf16x8;
typedef __attribute__((ext_vector_type(4))) float f32x4;

__device__ __forceinline__ u16 f2bf(float f) {
    uint32_t x = __float_as_uint(f);
    x += 0x7fffu + ((x >> 16) & 1u);      // round-to-nearest-even
    return (u16)(x >> 16);
}
__device__ __forceinline__ float bf2f(u16 u) {
    return __uint_as_float(((uint32_t)u) << 16);
}

// async global->LDS, 16B per lane; LDS dest = wave-uniform base + lane*16
__device__ __forceinline__ void async_cp16(const u16* g, u16* l) {
    auto* g1 = (const __attribute__((address_space(1))) u16*)g;
    auto* l3 = (__attribute__((address_space(3))) u16*)(uintptr_t)l;
    __builtin_amdgcn_global_load_lds((const __attribute__((address_space(1))) void*)g1,
                                     (__attribute__((address_space(3))) void*)l3,
                                     16, 0, 0);
}

// ---------------------------------------------------------------------------
// LDS tiles use 128-byte rows (BK=64 bf16) with XOR swizzle:
//   phys_byte = (row*128 + col) ^ ((row & 7) << 4)
// global_load_lds writes linearly (lane*16B), so the STAGE pre-applies the
// inverse permutation on the global SOURCE column (involution => same XOR):
//   staging lane covers linear LDS byte Y = p*4096 + tid*16
//   row(Y) = Y>>7 = p*32 + (tid>>3)   (p*32 keeps row&7 invariant)
//   col(Y) = (Y&127) ^ ((row&7)<<4) = ((tid&7)*16) ^ (((tid>>3)&7)<<4)
// Fragment reads XOR the same mask => 2-way bank aliasing only (free).
// ---------------------------------------------------------------------------

__global__ __launch_bounds__(256) void zero_kernel(float* __restrict__ p, int n) {
    int i = blockIdx.x * 256 + threadIdx.x;
    if (i < n) p[i] = 0.0f;
}

// fp32 -> bf16 pack: dst[r*cols+c] = bf16(src[r*src_ld + col0 + c])
__global__ __launch_bounds__(256) void conv_bf(
    const float* __restrict__ src, int src_ld, int col0, int cols,
    u16* __restrict__ dst, int total4)
{
    int i4 = blockIdx.x * 256 + threadIdx.x;
    if (i4 >= total4) return;
    int i = i4 * 4;
    int r = i / cols, c = i - r * cols;
    const float4 v = *(const float4*)(src + (size_t)r * src_ld + col0 + c);
    ushort4 o;
    o.x = f2bf(v.x); o.y = f2bf(v.y); o.z = f2bf(v.z); o.w = f2bf(v.w);
    *(ushort4*)(dst + i) = o;
}

// ---------------------------------------------------------------------------
// Fused Phase 1 MFMA GEMM over all three weight sets.
// 128x128 tile, BK=64, swizzled LDS, double-buffered. grid (72, B*Tc/128).
// ---------------------------------------------------------------------------
__global__ __launch_bounds__(256) void mfma_p1f(
    const u16* __restrict__ X, int t0, int tcshift,
    const u16* __restrict__ W1,
    const float* __restrict__ bs, const float* __restrict__ ba,
    const float* __restrict__ bo,
    u16* __restrict__ GI, size_t GI_elems)
{
    __shared__ u16 As[2][128 * 64];   // 16 KB each buf (swizzled 128B rows)
    __shared__ u16 Bs[2][128 * 64];   // total 64 KB exactly
    const int tid = threadIdx.x;
    const int which = blockIdx.x / 24;
    const int n0 = (blockIdx.x % 24) * 128;
    const int m0 = blockIdx.y * 128;
    const int tcmask = (1 << tcshift) - 1;

    const u16* W = W1 + (size_t)which * H3_ * E_;
    const float* bias = (which == 0) ? bs : (which == 1) ? ba : bo;
    u16* C = GI + (size_t)which * GI_elems;

    const int lane = tid & 63;
    const int wm = ((tid >> 6) & 1) * 64;
    const int wn = (tid >> 7) * 64;
    const int fr = lane & 15;            // fragment row (m for A, n for B)
    const int kq = (lane >> 4) * 8;      // k-quad elem offset
    const int ldsbase = (tid & 192) * 8; // wave-uniform LDS chunk base (elems)

    // staging geometry (round-invariant)
    const int srow = tid >> 3;                                   // 0..31
    const int sce  = (((tid & 7) * 16) ^ ((srow & 7) << 4)) >> 1; // elem col

    f32x4 acc[4][4] = {};

    auto stage = [&](int buf, int k0) {
#pragma unroll
        for (int p = 0; p < 4; ++p) {
            int mrow = m0 + p * 32 + srow;
            int ro = ((mrow >> tcshift) * T_ + t0 + (mrow & tcmask)) * E_;
            async_cp16(X + ro + k0 + sce, &As[buf][p * 2048 + ldsbase]);
            int nrow = n0 + p * 32 + srow;
            async_cp16(W + (size_t)nrow * E_ + k0 + sce, &Bs[buf][p * 2048 + ldsbase]);
        }
    };
    auto compute = [&](int buf) {
#pragma unroll
        for (int kk = 0; kk < 2; ++kk) {
            bf16x8 a[4], b[4];
#pragma unroll
            for (int i = 0; i < 4; ++i) {
                int ra = wm + i * 16 + fr;
                int oa = (ra * 128 + kk * 64 + kq * 2) ^ ((ra & 7) << 4);
                a[i] = *(const bf16x8*)((const char*)&As[buf][0] + oa);
                int rb = wn + i * 16 + fr;
                int ob = (rb * 128 + kk * 64 + kq * 2) ^ ((rb & 7) << 4);
                b[i] = *(const bf16x8*)((const char*)&Bs[buf][0] + ob);
            }
#pragma unroll
            for (int mt = 0; mt < 4; ++mt)
#pragma unroll
                for (int nt = 0; nt < 4; ++nt)
                    acc[mt][nt] = __builtin_amdgcn_mfma_f32_16x16x32_bf16(
                        a[mt], b[nt], acc[mt][nt], 0, 0, 0);
        }
    };

    stage(0, 0);
    __syncthreads();                 // drains vmcnt: buf0 ready
    int cur = 0;
    for (int k0 = 64; k0 < E_; k0 += 64) {
        stage(cur ^ 1, k0);          // issue next-tile loads (overlap w/ compute)
        compute(cur);
        __syncthreads();             // next buf ready, cur free
        cur ^= 1;
    }
    compute(cur);

#pragma unroll
    for (int mt = 0; mt < 4; ++mt)
#pragma unroll
        for (int nt = 0; nt < 4; ++nt) {
            int n = n0 + wn + nt * 16 + fr;
            float bv = bias[n];
#pragma unroll
            for (int i = 0; i < 4; ++i) {
                int m = m0 + wm + mt * 16 + (lane >> 4) * 4 + i;
                C[(size_t)m * H3_ + n] = f2bf(acc[mt][nt][i] + bv);
            }
        }
}

// ---------------------------------------------------------------------------
// Per-step MFMA GEMM over gathered state rows. 64x64 tile, BK=64, swizzled,
// grid (48, 20) = 960 blocks. G layout [1280 x 3072]:
//   [0,128) giS | [128,256) ghS | [256,384) giA | [384,512) ghA | [512,1280) ghO
// ---------------------------------------------------------------------------
__global__ __launch_bounds__(256) void mfma_step(
    const u16* __restrict__ Abf, const int* __restrict__ dig, int t,
    const u16* __restrict__ Whsi, const u16* __restrict__ Whs,
    const u16* __restrict__ Whai, const u16* __restrict__ Wha,
    const u16* __restrict__ Who, float* __restrict__ G)
{
    __shared__ u16 As[2][64 * 64];   // 8 KB each buf
    __shared__ u16 Bs[2][64 * 64];
    __shared__ int rowoff[64];
    const int tid = threadIdx.x;
    const int n0 = blockIdx.x * 64;
    const int row0 = blockIdx.y * 64;

    const u16* W;
    if      (row0 < 128) W = Whsi;
    else if (row0 < 256) W = Whs;
    else if (row0 < 384) W = Whai;
    else if (row0 < 512) W = Wha;
    else                 W = Who;

    if (tid < 64) {
        int mo = row0 + tid;
        int b, role;
        if (mo < 512) {
            b = mo & 127;
            int kind = mo >> 7;
            int spk = dig[(b * T_ + t) * 2 + 0];
            int adr = dig[(b * T_ + t) * 2 + 1];
            role = (kind == 0 || kind == 3) ? adr : spk;
        } else {
            int o = mo - 512;
            b = o / 6;
            int j = o - b * 6;
            int spk = dig[(b * T_ + t) * 2 + 0];
            int adr = dig[(b * T_ + t) * 2 + 1];
            int cnt = 0; role = 0;
            for (int r = 0; r < R_; ++r) {
                if (r != spk && r != adr) {
                    if (cnt == j) { role = r; break; }
                    ++cnt;
                }
            }
        }
        rowoff[tid] = (b * R_ + role) * H_;
    }
    __syncthreads();

    const int lane = tid & 63;
    const int wid = tid >> 6;
    const int wm = (wid & 1) * 32;
    const int wn = (wid >> 1) * 32;
    const int fr = lane & 15;
    const int kq = (lane >> 4) * 8;
    const int ldsbase = (tid & 192) * 8;

    const int srow = tid >> 3;                                    // 0..31
    const int sce  = (((tid & 7) * 16) ^ ((srow & 7) << 4)) >> 1; // elem col

    f32x4 acc[2][2] = {};

    auto stage = [&](int buf, int k0) {
#pragma unroll
        for (int p = 0; p < 2; ++p) {
            int r = p * 32 + srow;
            async_cp16(Abf + rowoff[r] + k0 + sce, &As[buf][p * 2048 + ldsbase]);
            async_cp16(W + (size_t)(n0 + r) * H_ + k0 + sce, &Bs[buf][p * 2048 + ldsbase]);
        }
    };
    auto compute = [&](int buf) {
#pragma unroll
        for (int kk = 0; kk < 2; ++kk) {
            bf16x8 a[2], b[2];
#pragma unroll
            for (int i = 0; i < 2; ++i) {
                int ra = wm + i * 16 + fr;
                int oa = (ra * 128 + kk * 64 + kq * 2) ^ ((ra & 7) << 4);
                a[i] = *(const bf16x8*)((const char*)&As[buf][0] + oa);
                int rb = wn + i * 16 + fr;
                int ob = (rb * 128 + kk * 64 + kq * 2) ^ ((rb & 7) << 4);
                b[i] = *(const bf16x8*)((const char*)&Bs[buf][0] + ob);
            }
#pragma unroll
            for (int mt = 0; mt < 2; ++mt)
#pragma unroll
                for (int nt = 0; nt < 2; ++nt)
                    acc[mt][nt] = __builtin_amdgcn_mfma_f32_16x16x32_bf16(
                        a[mt], b[nt], acc[mt][nt], 0, 0, 0);
        }
    };

    stage(0, 0);
    __syncthreads();
    int cur = 0;
    for (int k0 = 64; k0 < H_; k0 += 64) {
        stage(cur ^ 1, k0);
        compute(cur);
        __syncthreads();
        cur ^= 1;
    }
    compute(cur);

#pragma unroll
    for (int mt = 0; mt < 2; ++mt)
#pragma unroll
        for (int nt = 0; nt < 2; ++nt) {
            int n = n0 + wn + nt * 16 + fr;
#pragma unroll
            for (int i = 0; i < 4; ++i) {
                int mo = row0 + wm + mt * 16 + (lane >> 4) * 4 + i;
                G[(size_t)mo * H3_ + n] = acc[mt][nt][i];
            }
        }
}

// ---------------------------------------------------------------------------
// Gate kernel. Block per (b, r). Writes fp32 state (Anew) + bf16 copy (Abf).
// ---------------------------------------------------------------------------
__global__ __launch_bounds__(256) void gate_kernel(
    const float* __restrict__ Aold, float* __restrict__ Anew,
    u16* __restrict__ Abf,
    const int* __restrict__ dig, int t, int tloc, int Tc,
    const u16* __restrict__ GIX, const u16* __restrict__ GIA,
    const u16* __restrict__ GIO, const float* __restrict__ G,
    const float* __restrict__ ws_bhh, const float* __restrict__ wa_bhh,
    const float* __restrict__ wo_bhh)
{
    const int blk = blockIdx.x;       // b*R + r
    const int b = blk >> 3, r = blk & 7;
    const int spk = dig[(b * T_ + t) * 2 + 0];
    const int adr = dig[(b * T_ + t) * 2 + 1];
    const size_t gi_row = (size_t)(b * Tc + tloc) * H3_;

    const u16* gi_pre;
    const float* gi_add;   // may be null (others)
    const float* gh;
    const float* bhh;
    if (r == spk) {
        gi_pre = GIX + gi_row;
        gi_add = G + (size_t)b * H3_;
        gh     = G + (size_t)(128 + b) * H3_;
        bhh    = ws_bhh;
    } else if (r == adr) {
        gi_pre = GIA + gi_row;
        gi_add = G + (size_t)(256 + b) * H3_;
        gh     = G + (size_t)(384 + b) * H3_;
        bhh    = wa_bhh;
    } else {
        int oidx = r - (spk < r ? 1 : 0) - (adr < r ? 1 : 0);
        gi_pre = GIO + gi_row;
        gi_add = nullptr;
        gh     = G + (size_t)(512 + b * 6 + oidx) * H3_;
        bhh    = wo_bhh;
    }

    const size_t hoff = (size_t)(b * R_ + r) * H_;
    for (int i = threadIdx.x; i < H_; i += 256) {
        float gir = bf2f(gi_pre[i]);
        float giz = bf2f(gi_pre[H_ + i]);
        float gin = bf2f(gi_pre[2 * H_ + i]);
        if (gi_add) {
            gir += gi_add[i];
            giz += gi_add[H_ + i];
            gin += gi_add[2 * H_ + i];
        }
        float ghr = gh[i]          + bhh[i];
        float ghz = gh[H_ + i]     + bhh[H_ + i];
        float ghn = gh[2 * H_ + i] + bhh[2 * H_ + i];

        float rg = 1.0f / (1.0f + __expf(-(gir + ghr)));
        float zg = 1.0f / (1.0f + __expf(-(giz + ghz)));
        float ng = tanhf(gin + rg * ghn);
        float h  = Aold[hoff + i];
        float o  = (1.0f - zg) * ng + zg * h;
        Anew[hoff + i] = o;
        Abf[hoff + i]  = f2bf(o);
    }
}

// ---------------------------------------------------------------------------
extern "C" void kernel_launch(void* const* d_in, const int* in_sizes, int n_in,
                              void* d_out, int out_size, void* d_ws, size_t ws_size,
                              hipStream_t stream) {
    const float* enc    = (const float*)d_in[0];
    const int*   dig    = (const int*)d_in[1];
    const float* ws_ih  = (const float*)d_in[2];
    const float* ws_hh  = (const float*)d_in[3];
    const float* ws_bih = (const float*)d_in[4];
    const float* ws_bhh = (const float*)d_in[5];
    const float* wa_ih  = (const float*)d_in[6];
    const float* wa_hh  = (const float*)d_in[7];
    const float* wa_bih = (const float*)d_in[8];
    const float* wa_bhh = (const float*)d_in[9];
    const float* wo_ih  = (const float*)d_in[10];
    const float* wo_hh  = (const float*)d_in[11];
    const float* wo_bih = (const float*)d_in[12];
    const float* wo_bhh = (const float*)d_in[13];

    float* A0 = (float*)d_out;                    // (B, R, H) final output

    // ---- workspace layout (bytes) ----
    char* p = (char*)d_ws;
    auto take = [&](size_t bytes) { char* q = p; p += (bytes + 255) & ~(size_t)255; return q; };
    u16*   enc_bf = (u16*)  take((size_t)B_ * T_ * E_ * 2);          // 33.6 MB
    u16*   W1     = (u16*)  take((size_t)3 * H3_ * E_ * 2);          // 37.7 MB packed s|a|o
    u16*   W1s    = W1;
    u16*   W1a    = W1 + (size_t)H3_ * E_;
    u16*   W1o    = W1a + (size_t)H3_ * E_;
    u16*   Whsi   = (u16*)  take((size_t)H3_ * H_ * 2);              // 6.3 MB
    u16*   Whai   = (u16*)  take((size_t)H3_ * H_ * 2);
    u16*   Whs    = (u16*)  take((size_t)H3_ * H_ * 2);
    u16*   Wha    = (u16*)  take((size_t)H3_ * H_ * 2);
    u16*   Who    = (u16*)  take((size_t)H3_ * H_ * 2);
    u16*   Abf    = (u16*)  take((size_t)B_ * R_ * H_ * 2);          // 2 MB
    float* A1     = (float*)take((size_t)B_ * R_ * H_ * 4);          // 4 MB
    float* G      = (float*)take((size_t)1280 * H3_ * 4);            // 15.7 MB
    size_t fixed = (size_t)(p - (char*)d_ws);

    // chunk size: largest power-of-two Tc <= 64 fitting GI (3 sets, bf16)
    const size_t per_t = (size_t)3 * B_ * H3_ * 2;                   // 2.36 MB/step
    int Tc = 64;
    while (Tc > 1 && fixed + per_t * (size_t)Tc > ws_size) Tc >>= 1;
    int tcshift = 0;
    while ((1 << tcshift) < Tc) ++tcshift;
    const size_t GI_elems = (size_t)B_ * Tc * H3_;
    u16* GI  = (u16*)take(3 * GI_elems * 2);                         // packed X|A|O
    u16* GIX = GI;
    u16* GIA = GI + GI_elems;
    u16* GIO = GIA + GI_elems;

    dim3 blk(256);
    const size_t A_sz = (size_t)B_ * R_ * H_;

    // zero fp32 state (d_out) and bf16 state copy
    zero_kernel<<<dim3((int)((A_sz + 255) / 256)), blk, 0, stream>>>(A0, (int)A_sz);
    zero_kernel<<<dim3((int)((A_sz / 2 + 255) / 256)), blk, 0, stream>>>((float*)Abf, (int)(A_sz / 2));

    // ---- one-time bf16 conversions ----
    {
        int t4;
        t4 = B_ * T_ * E_ / 4;
        conv_bf<<<dim3((t4 + 255) / 256), blk, 0, stream>>>(enc, E_, 0, E_, enc_bf, t4);
        t4 = H3_ * E_ / 4;
        conv_bf<<<dim3((t4 + 255) / 256), blk, 0, stream>>>(ws_ih, E_ + H_, 0, E_, W1s, t4);
        conv_bf<<<dim3((t4 + 255) / 256), blk, 0, stream>>>(wa_ih, E_ + H_, 0, E_, W1a, t4);
        conv_bf<<<dim3((t4 + 255) / 256), blk, 0, stream>>>(wo_ih, E_, 0, E_, W1o, t4);
        t4 = H3_ * H_ / 4;
        conv_bf<<<dim3((t4 + 255) / 256), blk, 0, stream>>>(ws_ih, E_ + H_, E_, H_, Whsi, t4);
        conv_bf<<<dim3((t4 + 255) / 256), blk, 0, stream>>>(wa_ih, E_ + H_, E_, H_, Whai, t4);
        conv_bf<<<dim3((t4 + 255) / 256), blk, 0, stream>>>(ws_hh, H_, 0, H_, Whs, t4);
        conv_bf<<<dim3((t4 + 255) / 256), blk, 0, stream>>>(wa_hh, H_, 0, H_, Wha, t4);
        conv_bf<<<dim3((t4 + 255) / 256), blk, 0, stream>>>(wo_hh, H_, 0, H_, Who, t4);
    }

    float* Aold = A0;
    float* Anew = A1;
    for (int t0 = 0; t0 < T_; t0 += Tc) {
        // Phase 1 (chunk): all three input-side GEMMs fused in one dispatch.
        dim3 g1(72, (B_ * Tc) / 128);
        mfma_p1f<<<g1, blk, 0, stream>>>(enc_bf, t0, tcshift, W1,
                                         ws_bih, wa_bih, wo_bih, GI, GI_elems);

        // Phase 2: sequential recurrence within the chunk.
        for (int t = t0; t < t0 + Tc; ++t) {
            mfma_step<<<dim3(48, 20), blk, 0, stream>>>(
                Abf, dig, t, Whsi, Whs, Whai, Wha, Who, G);
            gate_kernel<<<dim3(B_ * R_), blk, 0, stream>>>(
                Aold, Anew, Abf, dig, t, t - t0, Tc, GIX, GIA, GIO, G,
                ws_bhh, wa_bhh, wo_bhh);
            float* tmp = Aold; Aold = Anew; Anew = tmp;
        }
    }
    // T_ = 64 total steps (even): final state lands in A0 == d_out.
}